// Round 2
// baseline (2113.498 us; speedup 1.0000x reference)
//
#include <hip/hip_runtime.h>
#include <hip/hip_bf16.h>

// Problem constants
#define NT   1000
#define NS   2048
#define NH   16
#define NR   8
#define HS   256
#define TOUT 993   // NT - NR + 1

typedef __attribute__((ext_vector_type(8))) short short8;
typedef __attribute__((ext_vector_type(4))) float f32x4;

__device__ __forceinline__ ushort f2bf(float f) {
    union { float f; unsigned int u; } v; v.f = f;
    unsigned int u = v.u;
    return (ushort)((u + 0x7fffu + ((u >> 16) & 1u)) >> 16);
}
__device__ __forceinline__ float bf2f(ushort u) {
    union { unsigned int i; float f; } v; v.i = ((unsigned int)u) << 16; return v.f;
}
__device__ __forceinline__ float sigf(float x) { return 1.f / (1.f + __expf(-x)); }
__device__ __forceinline__ float fast_tanh(float z) {
    float e = __expf(2.f * z);
    return 1.f - 2.f * __builtin_amdgcn_rcpf(e + 1.f);
}

// ---------------- Kernel A: per-site setup (all fp32 inputs) ----------------
// state = xc@W_fc + b_fc; stateK = state + b_kin; hG = tanh(state);
// pG = hG@W_g + b_g, pR = hG@W_r + b_r; gates; wr (softmax/cumsum); wrga = wr*ga.
// Block 0 additionally transposes W_kout -> bf16 Wt_g[col][264].
__global__ __launch_bounds__(256) void kA(
    const float* __restrict__ xc, const float* __restrict__ W_fc, const float* __restrict__ b_fc,
    const float* __restrict__ W_r, const float* __restrict__ b_r,
    const float* __restrict__ W_g, const float* __restrict__ b_g,
    const float* __restrict__ b_kin, const float* __restrict__ W_kout,
    float* __restrict__ stateK, float* __restrict__ params, ushort* __restrict__ Wt_g)
{
    __shared__ float xcs[32];
    __shared__ float hG[256];
    __shared__ float pGR[288];
    const int s = blockIdx.x, tid = threadIdx.x;

    if (tid < 32) xcs[tid] = xc[s * 32 + tid];
    __syncthreads();

    float acc = b_fc[tid];
#pragma unroll 8
    for (int k = 0; k < 32; ++k) acc = fmaf(xcs[k], W_fc[k * 256 + tid], acc);
    stateK[s * 256 + tid] = acc + b_kin[tid];
    hG[tid] = tanhf(acc);
    __syncthreads();

    for (int j = tid; j < 288; j += 256) {
        const float* W = (j < 144) ? W_g : W_r;
        const float* b = (j < 144) ? b_g : b_r;
        int col = (j < 144) ? j : (j - 144);
        float a = b[col];
#pragma unroll 4
        for (int k = 0; k < 256; ++k) a = fmaf(hG[k], W[k * 144 + col], a);
        pGR[j] = a;
    }
    __syncthreads();

    if (tid < 16) {
        const int h = tid;
        float g0 = pGR[h],       g1 = pGR[16 + h],  g2 = pGR[32 + h];
        float g3 = pGR[48 + h],  g4 = pGR[64 + h],  g5 = pGR[80 + h];
        float g6 = pGR[96 + h],  g7 = pGR[112 + h], g8 = pGR[128 + h];
        float kp = sigf(g0), ksg = sigf(g1), kd = sigf(g2), gd = sigf(g3);
        float t4 = sigf(g4) * 10.f; float gl = t4 * t4 * t4;
        float qb = fmaxf(g5, 0.f) * 0.1f;
        float gi = fminf(fmaxf(g7 * (1.f / 6.f) + 0.5f, 0.f), 1.f) * 0.5f;
        float ge = fmaxf(g8, 0.f);
        // ga = softmax over 16 heads (lanes 0..15 of wave 0)
        float m = g6;
        for (int o = 1; o < 16; o <<= 1) m = fmaxf(m, __shfl_xor(m, o));
        float e = __expf(g6 - m), esum = e;
        for (int o = 1; o < 16; o <<= 1) esum += __shfl_xor(esum, o);
        float ga = e / esum;
        // wr from pR row h (9 logits -> softmax -> cumsum -> triangle -> renorm)
        float r[9], rm = -1e30f;
#pragma unroll
        for (int i = 0; i < 9; ++i) { r[i] = pGR[144 + h * 9 + i]; rm = fmaxf(rm, r[i]); }
        float er[9], es = 0.f;
#pragma unroll
        for (int i = 0; i < 9; ++i) { er[i] = __expf(r[i] - rm); es += er[i]; }
        float inv_es = 1.f / es, c = 0.f, wsum = 0.f, w[8];
#pragma unroll
        for (int i = 0; i < 8; ++i) {
            float si = er[i] * inv_es; c += si;
            float wi = fminf(c, 1.f - c + si);
            w[i] = wi; wsum += wi;
        }
        const int base = s * 16 + h;
        params[0 * 32768 + base] = kp;  params[1 * 32768 + base] = ksg;
        params[2 * 32768 + base] = kd;  params[3 * 32768 + base] = gd;
        params[4 * 32768 + base] = gl;  params[5 * 32768 + base] = qb;
        params[6 * 32768 + base] = gi;  params[7 * 32768 + base] = ge;
        float sc = ga / wsum;
#pragma unroll
        for (int i = 0; i < 8; ++i) params[(8 + i) * 32768 + base] = w[i] * sc;
    }

    if (s == 0) {
        for (int i = tid; i < 48 * 256; i += 256) {
            int k = i / 48, col = i - k * 48;
            Wt_g[col * 264 + k] = f2bf(W_kout[i]);   // transpose to bf16, padded stride 264
        }
    }
}

// ---------------- Kernel B: h1 = tanh(stateK + f@W_kin); pK = h1@W_kout; km/ki/ke ----------------
// One block per (t, 64-site tile). MFMA 16x16x32 bf16, K=256, N=48 (3 n-tiles).
__global__ __launch_bounds__(256) void kB(
    const float* __restrict__ x,
    const float* __restrict__ stateK, const float* __restrict__ W_kin, const float* __restrict__ b_kout,
    const ushort* __restrict__ Wt_g,
    ushort* __restrict__ K3, float* __restrict__ PsA, float* __restrict__ PlA, float* __restrict__ EvA)
{
    __shared__ ushort h1[64 * 264];   // A tiles, padded stride (16B-aligned rows)
    __shared__ ushort Wt[48 * 264];   // W_kout^T (bf16)
    __shared__ ushort outT[64 * 48];  // output staging (matches global layout)
    const int tid = threadIdx.x;
    const int t = blockIdx.x >> 5;
    const int s0 = (blockIdx.x & 31) << 6;

    // stage transposed W_kout (25,344 B) as uint2
    for (int i = tid; i < 3168; i += 256)
        ((uint2*)Wt)[i] = ((const uint2*)Wt_g)[i];

    // Ps / Pl / Ev for this tile's 64 sites
    if (tid < 64) {
        int s = s0 + tid;
        size_t xb = ((size_t)(t * 2048 + s)) * 6;
        float2 u01 = *(const float2*)(x + xb);      // Prcp, Evp
        float2 u23 = *(const float2*)(x + xb + 2);  // T1, T2
        float Prcp = u01.x, Evp = u01.y, T1 = u23.x, T2 = u23.y;
        float fl = T2 / (T2 - T1 + 1e-5f);
        fl = fminf(fmaxf(fl, 0.f), 1.f);
        int ts = t * 2048 + s;
        PsA[ts] = Prcp * (1.f - fl);
        PlA[ts] = Prcp * fl;
        EvA[ts] = Evp;
    }

    // h1 tile: 4 threads per row, 64 k each
    {
        const int row = tid >> 2, kc = (tid & 3) << 6;
        const int s = s0 + row;
        size_t xb = ((size_t)(t * 2048 + s)) * 6;
        float2 u23 = *(const float2*)(x + xb + 2);  // T1, T2
        float2 u45 = *(const float2*)(x + xb + 4);  // Rad, Hum
        float x0 = u23.x, x1 = u23.y, x2 = u45.x, x3 = u45.y;
        const float* st = stateK + s * 256 + kc;
        const float* wk = W_kin + kc;
        ushort* hrow = h1 + row * 264 + kc;
#pragma unroll 4
        for (int kk = 0; kk < 64; kk += 4) {
            float4 sv = *(const float4*)(st + kk);
            float4 w0 = *(const float4*)(wk + kk);
            float4 w1 = *(const float4*)(wk + 256 + kk);
            float4 w2 = *(const float4*)(wk + 512 + kk);
            float4 w3 = *(const float4*)(wk + 768 + kk);
            float z0 = sv.x + x0 * w0.x + x1 * w1.x + x2 * w2.x + x3 * w3.x;
            float z1 = sv.y + x0 * w0.y + x1 * w1.y + x2 * w2.y + x3 * w3.y;
            float z2 = sv.z + x0 * w0.z + x1 * w1.z + x2 * w2.z + x3 * w3.z;
            float z3 = sv.w + x0 * w0.w + x1 * w1.w + x2 * w2.w + x3 * w3.w;
            ushort4 o;
            o.x = f2bf(fast_tanh(z0)); o.y = f2bf(fast_tanh(z1));
            o.z = f2bf(fast_tanh(z2)); o.w = f2bf(fast_tanh(z3));
            *(ushort4*)(hrow + kk) = o;
        }
    }
    __syncthreads();

    // MFMA: wave wv owns rows [wv*16, wv*16+16), all 48 cols
    // A: A[m=lane&15][k=quad*8+j]; B: B[k=quad*8+j][n=lane&15]; D: col=lane&15,row=quad*4+reg
    const int wv = tid >> 6, lane = tid & 63;
    const int mi = lane & 15, quad = lane >> 4;
    const ushort* Ab = h1 + (wv * 16 + mi) * 264 + quad * 8;
    const ushort* Bb = Wt + mi * 264 + quad * 8;
    f32x4 acc0 = {0.f, 0.f, 0.f, 0.f}, acc1 = {0.f, 0.f, 0.f, 0.f}, acc2 = {0.f, 0.f, 0.f, 0.f};
#pragma unroll
    for (int kk = 0; kk < 256; kk += 32) {
        short8 a  = *(const short8*)(Ab + kk);
        short8 b0 = *(const short8*)(Bb + kk);
        short8 b1 = *(const short8*)(Bb + 16 * 264 + kk);
        short8 b2 = *(const short8*)(Bb + 32 * 264 + kk);
        acc0 = __builtin_amdgcn_mfma_f32_16x16x32_bf16(a, b0, acc0, 0, 0, 0);
        acc1 = __builtin_amdgcn_mfma_f32_16x16x32_bf16(a, b1, acc1, 0, 0, 0);
        acc2 = __builtin_amdgcn_mfma_f32_16x16x32_bf16(a, b2, acc2, 0, 0, 0);
    }

    // epilogue: add bias, activation, stage to outT ([sl][48] == global layout)
    {
        float b0 = b_kout[mi], b1 = b_kout[16 + mi], b2 = b_kout[32 + mi];
#pragma unroll
        for (int reg = 0; reg < 4; ++reg) {
            int sl = wv * 16 + quad * 4 + reg;
            float pk0 = acc0[reg] + b0;
            float pk1 = acc1[reg] + b1;
            float pk2 = acc2[reg] + b2;
            outT[sl * 48 + mi]      = f2bf(__expf(pk0));        // km
            outT[sl * 48 + 16 + mi] = f2bf(fmaxf(pk1, 0.f));    // ki
            outT[sl * 48 + 32 + mi] = f2bf(__expf(pk2));        // ke
        }
    }
    __syncthreads();

    // coalesced store: 64 rows x 96 B contiguous
    {
        uint2* dst = (uint2*)(K3 + ((size_t)t * 2048 + s0) * 48);
        const uint2* src = (const uint2*)outT;
        for (int i = tid; i < 768; i += 256) dst[i] = src[i];
    }
}

// ---------------- Kernel C: sequential scan + in-register FIR + head-sum ----------------
// Thread = (site, head). Lanes: h = lane&15, 4 sites per wave. 512 blocks x 64.
__global__ __launch_bounds__(64) void kC(
    const ushort* __restrict__ K3, const float* __restrict__ PsA, const float* __restrict__ PlA,
    const float* __restrict__ EvA, const float* __restrict__ params, float* __restrict__ yOut)
{
    const int gid = blockIdx.x * 64 + threadIdx.x;
    const int h = gid & 15, s = gid >> 4;

    const float kp  = params[0 * 32768 + gid];
    const float ksg = params[1 * 32768 + gid];
    const float kd  = params[2 * 32768 + gid];
    const float gd  = params[3 * 32768 + gid];
    const float gl  = params[4 * 32768 + gid];
    const float qbv = params[5 * 32768 + gid];
    const float gi  = params[6 * 32768 + gid];
    const float ge  = params[7 * 32768 + gid];
    float wrga[8];
#pragma unroll
    for (int i = 0; i < 8; ++i) wrga[i] = params[(8 + i) * 32768 + gid];

    const ushort* kmp = K3 + (size_t)s * 48 + h;
    float Sf = 0.f, Ss = 0.f, Sg = 0.f;
    float qh[8];

    for (int tb = 0; tb < 125; ++tb) {
#pragma unroll
        for (int i = 0; i < 8; ++i) {
            const int t = tb * 8 + i;
            const size_t ro = (size_t)t * (2048 * 48);
            float km = bf2f(kmp[ro]);
            float ki = bf2f(kmp[ro + 16]);
            float ke = bf2f(kmp[ro + 32]);
            const int ts = t * 2048 + s;
            float ps = PsA[ts], pl = PlA[ts], ev = EvA[ts];

            Sf += ps;
            float qf = fminf(Sf, km); Sf -= qf;
            float inflow = qf + pl;
            float qd = inflow * gi;
            Ss += inflow * (1.f - gi);
            float E = fminf(fmaxf(Ss, 0.f), ev * ke * ge); Ss -= E;
            float qi = fminf(ki, fmaxf(Ss, 0.f)); Ss -= qi;
            float qp = kp * fmaxf(Ss - gl, 0.f);
            float qsa = ksg * fminf(fmaxf(Ss, 0.f), gl);
            Ss -= qp + qsa;
            Sg += qsa * gd;
            float qg = kd * Sg + qbv;
            Sg *= (1.f - kd);
            float q = qp + qsa * (1.f - gd) + qg + qd + qi;
            qh[i] = q;

            if (t >= 7) {
                float v = 0.f;
#pragma unroll
                for (int k = 0; k < 8; ++k) v = fmaf(wrga[k], qh[(i - k) & 7], v);
                v += __shfl_xor(v, 1); v += __shfl_xor(v, 2);
                v += __shfl_xor(v, 4); v += __shfl_xor(v, 8);
                if (h == 0) yOut[(size_t)(t - 7) * 2048 + s] = v;
            }
        }
    }
}

// ---------------- launch ----------------
extern "C" void kernel_launch(void* const* d_in, const int* in_sizes, int n_in,
                              void* d_out, int out_size, void* d_ws, size_t ws_size,
                              hipStream_t stream) {
    const float* x      = (const float*)d_in[0];
    const float* xc     = (const float*)d_in[1];
    const float* W_fc   = (const float*)d_in[2];
    const float* b_fc   = (const float*)d_in[3];
    const float* W_r    = (const float*)d_in[4];
    const float* b_r    = (const float*)d_in[5];
    const float* W_g    = (const float*)d_in[6];
    const float* b_g    = (const float*)d_in[7];
    const float* W_kin  = (const float*)d_in[8];
    const float* b_kin  = (const float*)d_in[9];
    const float* W_kout = (const float*)d_in[10];
    const float* b_kout = (const float*)d_in[11];
    float* yOut = (float*)d_out;

    char* ws = (char*)d_ws;
    float*  stateK = (float*)(ws + 0);                       // 2,097,152 B
    float*  params = (float*)(ws + (2 << 20));               // 2,097,152 B (16 x 32768 fp32)
    ushort* Wt_g   = (ushort*)(ws + (4 << 20));              // 25,344 B (reserve 128 KiB)
    float*  PsA    = (float*)(ws + (4 << 20) + (128 << 10)); // 8,192,000 B each
    float*  PlA    = PsA + (size_t)NT * NS;
    float*  EvA    = PlA + (size_t)NT * NS;
    ushort* K3     = (ushort*)(EvA + (size_t)NT * NS);       // 196,608,000 B

    hipLaunchKernelGGL(kA, dim3(2048), dim3(256), 0, stream,
                       xc, W_fc, b_fc, W_r, b_r, W_g, b_g, b_kin, W_kout,
                       stateK, params, Wt_g);
    hipLaunchKernelGGL(kB, dim3(32000), dim3(256), 0, stream,
                       x, stateK, W_kin, b_kout, Wt_g, K3, PsA, PlA, EvA);
    hipLaunchKernelGGL(kC, dim3(512), dim3(64), 0, stream,
                       K3, PsA, PlA, EvA, params, yOut);
}

// Round 3
// 983.936 us; speedup vs baseline: 2.1480x; 2.1480x over previous
//
#include <hip/hip_runtime.h>
#include <hip/hip_bf16.h>

// Problem constants
#define NT   1000
#define NS   2048
#define NH   16
#define NR   8
#define HS   256
#define TOUT 993   // NT - NR + 1

typedef __attribute__((ext_vector_type(8))) short short8;
typedef __attribute__((ext_vector_type(4))) float f32x4;

__device__ __forceinline__ ushort f2bf(float f) {
    union { float f; unsigned int u; } v; v.f = f;
    unsigned int u = v.u;
    return (ushort)((u + 0x7fffu + ((u >> 16) & 1u)) >> 16);
}
__device__ __forceinline__ float bf2f(ushort u) {
    union { unsigned int i; float f; } v; v.i = ((unsigned int)u) << 16; return v.f;
}
__device__ __forceinline__ float sigf(float x) { return 1.f / (1.f + __expf(-x)); }
__device__ __forceinline__ float fast_tanh(float z) {
    float e = __expf(2.f * z);
    return 1.f - 2.f * __builtin_amdgcn_rcpf(e + 1.f);
}

// ---------------- Kernel A: per-site setup (fp32 inputs) ----------------
__global__ __launch_bounds__(256) void kA(
    const float* __restrict__ xc, const float* __restrict__ W_fc, const float* __restrict__ b_fc,
    const float* __restrict__ W_r, const float* __restrict__ b_r,
    const float* __restrict__ W_g, const float* __restrict__ b_g,
    const float* __restrict__ b_kin, const float* __restrict__ W_kout,
    float* __restrict__ stateK, float* __restrict__ params, ushort* __restrict__ Wt_g)
{
    __shared__ float xcs[32];
    __shared__ float hG[256];
    __shared__ float pGR[288];
    const int s = blockIdx.x, tid = threadIdx.x;

    if (tid < 32) xcs[tid] = xc[s * 32 + tid];
    __syncthreads();

    float acc = b_fc[tid];
#pragma unroll 8
    for (int k = 0; k < 32; ++k) acc = fmaf(xcs[k], W_fc[k * 256 + tid], acc);
    stateK[s * 256 + tid] = acc + b_kin[tid];
    hG[tid] = tanhf(acc);
    __syncthreads();

    for (int j = tid; j < 288; j += 256) {
        const float* W = (j < 144) ? W_g : W_r;
        const float* b = (j < 144) ? b_g : b_r;
        int col = (j < 144) ? j : (j - 144);
        float a = b[col];
#pragma unroll 4
        for (int k = 0; k < 256; ++k) a = fmaf(hG[k], W[k * 144 + col], a);
        pGR[j] = a;
    }
    __syncthreads();

    if (tid < 16) {
        const int h = tid;
        float g0 = pGR[h],       g1 = pGR[16 + h],  g2 = pGR[32 + h];
        float g3 = pGR[48 + h],  g4 = pGR[64 + h],  g5 = pGR[80 + h];
        float g6 = pGR[96 + h],  g7 = pGR[112 + h], g8 = pGR[128 + h];
        float kp = sigf(g0), ksg = sigf(g1), kd = sigf(g2), gd = sigf(g3);
        float t4 = sigf(g4) * 10.f; float gl = t4 * t4 * t4;
        float qb = fmaxf(g5, 0.f) * 0.1f;
        float gi = fminf(fmaxf(g7 * (1.f / 6.f) + 0.5f, 0.f), 1.f) * 0.5f;
        float ge = fmaxf(g8, 0.f);
        float m = g6;
        for (int o = 1; o < 16; o <<= 1) m = fmaxf(m, __shfl_xor(m, o));
        float e = __expf(g6 - m), esum = e;
        for (int o = 1; o < 16; o <<= 1) esum += __shfl_xor(esum, o);
        float ga = e / esum;
        float r[9], rm = -1e30f;
#pragma unroll
        for (int i = 0; i < 9; ++i) { r[i] = pGR[144 + h * 9 + i]; rm = fmaxf(rm, r[i]); }
        float er[9], es = 0.f;
#pragma unroll
        for (int i = 0; i < 9; ++i) { er[i] = __expf(r[i] - rm); es += er[i]; }
        float inv_es = 1.f / es, c = 0.f, wsum = 0.f, w[8];
#pragma unroll
        for (int i = 0; i < 8; ++i) {
            float si = er[i] * inv_es; c += si;
            float wi = fminf(c, 1.f - c + si);
            w[i] = wi; wsum += wi;
        }
        const int base = s * 16 + h;
        params[0 * 32768 + base] = kp;  params[1 * 32768 + base] = ksg;
        params[2 * 32768 + base] = kd;  params[3 * 32768 + base] = gd;
        params[4 * 32768 + base] = gl;  params[5 * 32768 + base] = qb;
        params[6 * 32768 + base] = gi;  params[7 * 32768 + base] = ge;
        float sc = ga / wsum;
#pragma unroll
        for (int i = 0; i < 8; ++i) params[(8 + i) * 32768 + base] = w[i] * sc;
    }

    if (s == 0) {
        for (int i = tid; i < 48 * 256; i += 256) {
            int k = i / 48, col = i - k * 48;
            Wt_g[col * 264 + k] = f2bf(W_kout[i]);   // transpose to bf16, stride 264
        }
    }
}

// ---------------- Kernel B v2: register-resident A-fragments, 1 barrier/block ----------------
// Block = 4 waves, site-tile of 16 sites, 20 t's (5 per wave). LDS = W_kout^T only.
// Lane (quad,mi) computes h1[site=mi][k=quad*8+j+32*kk] directly into the MFMA
// A-fragment layout; D (col=mi, row=quad*4+reg) stored per-lane, coalesced.
__global__ __launch_bounds__(256) void kB(
    const float* __restrict__ x,
    const float* __restrict__ stateK, const float* __restrict__ W_kin, const float* __restrict__ b_kout,
    const ushort* __restrict__ Wt_g,
    unsigned int* __restrict__ kmki, ushort* __restrict__ keA,
    float* __restrict__ PsA, float* __restrict__ PlA, float* __restrict__ EvA)
{
    __shared__ ushort Wt[48 * 264];   // W_kout^T (bf16), 25,344 B
    const int tid = threadIdx.x;
    const int st = blockIdx.x & 127;      // site tile
    const int tg = blockIdx.x >> 7;       // t group (0..49)
    const int s0 = st << 4;

    for (int i = tid; i < 3168; i += 256)
        ((uint2*)Wt)[i] = ((const uint2*)Wt_g)[i];
    __syncthreads();

    const int wv = tid >> 6, lane = tid & 63;
    const int mi = lane & 15, quad = lane >> 4;
    const int site = s0 + mi;

    const float bo0 = b_kout[mi], bo1 = b_kout[16 + mi], bo2 = b_kout[32 + mi];
    const float* stp = stateK + site * 256 + quad * 8;
    const float* wkp = W_kin + quad * 8;
    const ushort* Wt0 = Wt + mi * 264 + quad * 8;

    const int tbase = tg * 20 + wv * 5;
#pragma unroll 1
    for (int ti = 0; ti < 5; ++ti) {
        const int t = tbase + ti;
        // x features for site mi
        size_t xb = ((size_t)(t * 2048 + site)) * 6;
        float2 u23 = *(const float2*)(x + xb + 2);
        float2 u45 = *(const float2*)(x + xb + 4);
        float x0 = u23.x, x1 = u23.y, x2 = u45.x, x3 = u45.y;
        if (lane < 16) {       // quad 0 also emits Ps/Pl/Ev
            float2 u01 = *(const float2*)(x + xb);
            float fl = u23.y / (u23.y - u23.x + 1e-5f);
            fl = fminf(fmaxf(fl, 0.f), 1.f);
            int ts = t * 2048 + site;
            PsA[ts] = u01.x * (1.f - fl);
            PlA[ts] = u01.x * fl;
            EvA[ts] = u01.y;
        }

        f32x4 acc0 = {0.f,0.f,0.f,0.f}, acc1 = {0.f,0.f,0.f,0.f}, acc2 = {0.f,0.f,0.f,0.f};
#pragma unroll
        for (int kk = 0; kk < 8; ++kk) {
            const int ko = kk * 32;
            float4 sa  = *(const float4*)(stp + ko);
            float4 sb  = *(const float4*)(stp + ko + 4);
            float4 w0a = *(const float4*)(wkp + ko);
            float4 w0b = *(const float4*)(wkp + ko + 4);
            float4 w1a = *(const float4*)(wkp + 256 + ko);
            float4 w1b = *(const float4*)(wkp + 256 + ko + 4);
            float4 w2a = *(const float4*)(wkp + 512 + ko);
            float4 w2b = *(const float4*)(wkp + 512 + ko + 4);
            float4 w3a = *(const float4*)(wkp + 768 + ko);
            float4 w3b = *(const float4*)(wkp + 768 + ko + 4);
            float z0 = sa.x + x0*w0a.x + x1*w1a.x + x2*w2a.x + x3*w3a.x;
            float z1 = sa.y + x0*w0a.y + x1*w1a.y + x2*w2a.y + x3*w3a.y;
            float z2 = sa.z + x0*w0a.z + x1*w1a.z + x2*w2a.z + x3*w3a.z;
            float z3 = sa.w + x0*w0a.w + x1*w1a.w + x2*w2a.w + x3*w3a.w;
            float z4 = sb.x + x0*w0b.x + x1*w1b.x + x2*w2b.x + x3*w3b.x;
            float z5 = sb.y + x0*w0b.y + x1*w1b.y + x2*w2b.y + x3*w3b.y;
            float z6 = sb.z + x0*w0b.z + x1*w1b.z + x2*w2b.z + x3*w3b.z;
            float z7 = sb.w + x0*w0b.w + x1*w1b.w + x2*w2b.w + x3*w3b.w;
            short8 a;
            a[0] = (short)f2bf(fast_tanh(z0)); a[1] = (short)f2bf(fast_tanh(z1));
            a[2] = (short)f2bf(fast_tanh(z2)); a[3] = (short)f2bf(fast_tanh(z3));
            a[4] = (short)f2bf(fast_tanh(z4)); a[5] = (short)f2bf(fast_tanh(z5));
            a[6] = (short)f2bf(fast_tanh(z6)); a[7] = (short)f2bf(fast_tanh(z7));
            short8 b0 = *(const short8*)(Wt0 + ko);
            short8 b1 = *(const short8*)(Wt0 + 16 * 264 + ko);
            short8 b2 = *(const short8*)(Wt0 + 32 * 264 + ko);
            acc0 = __builtin_amdgcn_mfma_f32_16x16x32_bf16(a, b0, acc0, 0, 0, 0);
            acc1 = __builtin_amdgcn_mfma_f32_16x16x32_bf16(a, b1, acc1, 0, 0, 0);
            acc2 = __builtin_amdgcn_mfma_f32_16x16x32_bf16(a, b2, acc2, 0, 0, 0);
        }

        // D: row = quad*4+reg (site_local), col = mi (head). Coalesced dword/b16 stores.
#pragma unroll
        for (int reg = 0; reg < 4; ++reg) {
            const int sl = quad * 4 + reg;
            float km = __expf(acc0[reg] + bo0);
            float ki = fmaxf(acc1[reg] + bo1, 0.f);
            float ke = __expf(acc2[reg] + bo2);
            const size_t idx = (size_t)t * 32768 + (s0 + sl) * 16 + mi;
            kmki[idx] = (unsigned int)f2bf(km) | ((unsigned int)f2bf(ki) << 16);
            keA[idx]  = f2bf(ke);
        }
    }
}

// ---------------- Kernel C v2: scan + FIR, coalesced loads + 8-ahead prefetch ----------------
__global__ __launch_bounds__(64) void kC(
    const unsigned int* __restrict__ kmki, const ushort* __restrict__ keA,
    const float* __restrict__ PsA, const float* __restrict__ PlA, const float* __restrict__ EvA,
    const float* __restrict__ params, float* __restrict__ yOut)
{
    const int gid = blockIdx.x * 64 + threadIdx.x;
    const int h = gid & 15, s = gid >> 4;

    const float kp  = params[0 * 32768 + gid];
    const float ksg = params[1 * 32768 + gid];
    const float kd  = params[2 * 32768 + gid];
    const float gd  = params[3 * 32768 + gid];
    const float gl  = params[4 * 32768 + gid];
    const float qbv = params[5 * 32768 + gid];
    const float gi  = params[6 * 32768 + gid];
    const float ge  = params[7 * 32768 + gid];
    float wrga[8];
#pragma unroll
    for (int i = 0; i < 8; ++i) wrga[i] = params[(8 + i) * 32768 + gid];

    float Sf = 0.f, Ss = 0.f, Sg = 0.f;
    float qh[8];

    unsigned int ca[8]; ushort ce[8]; float cps[8], cpl[8], cev[8];
#pragma unroll
    for (int i = 0; i < 8; ++i) {
        ca[i] = kmki[(size_t)i * 32768 + gid];
        ce[i] = keA[(size_t)i * 32768 + gid];
        int ts = i * 2048 + s;
        cps[i] = PsA[ts]; cpl[i] = PlA[ts]; cev[i] = EvA[ts];
    }

    for (int tb = 0; tb < 125; ++tb) {
        unsigned int na[8]; ushort ne[8]; float nps[8], npl[8], nev[8];
        const int nb = (tb < 124) ? (tb + 1) * 8 : 0;
#pragma unroll
        for (int i = 0; i < 8; ++i) {
            na[i] = kmki[(size_t)(nb + i) * 32768 + gid];
            ne[i] = keA[(size_t)(nb + i) * 32768 + gid];
            int ts = (nb + i) * 2048 + s;
            nps[i] = PsA[ts]; npl[i] = PlA[ts]; nev[i] = EvA[ts];
        }
#pragma unroll
        for (int i = 0; i < 8; ++i) {
            const int t = tb * 8 + i;
            float km = bf2f((ushort)(ca[i] & 0xffffu));
            float ki = bf2f((ushort)(ca[i] >> 16));
            float ke = bf2f(ce[i]);
            float ps = cps[i], pl = cpl[i], ev = cev[i];

            Sf += ps;
            float qf = fminf(Sf, km); Sf -= qf;
            float inflow = qf + pl;
            float qd = inflow * gi;
            Ss += inflow * (1.f - gi);
            float E = fminf(fmaxf(Ss, 0.f), ev * ke * ge); Ss -= E;
            float qi = fminf(ki, fmaxf(Ss, 0.f)); Ss -= qi;
            float qp = kp * fmaxf(Ss - gl, 0.f);
            float qsa = ksg * fminf(fmaxf(Ss, 0.f), gl);
            Ss -= qp + qsa;
            Sg += qsa * gd;
            float qg = kd * Sg + qbv;
            Sg *= (1.f - kd);
            float q = qp + qsa * (1.f - gd) + qg + qd + qi;
            qh[i] = q;

            if (t >= 7) {
                float v = 0.f;
#pragma unroll
                for (int k = 0; k < 8; ++k) v = fmaf(wrga[k], qh[(i - k) & 7], v);
                v += __shfl_xor(v, 1); v += __shfl_xor(v, 2);
                v += __shfl_xor(v, 4); v += __shfl_xor(v, 8);
                if (h == 0) yOut[(size_t)(t - 7) * 2048 + s] = v;
            }
        }
#pragma unroll
        for (int i = 0; i < 8; ++i) {
            ca[i] = na[i]; ce[i] = ne[i];
            cps[i] = nps[i]; cpl[i] = npl[i]; cev[i] = nev[i];
        }
    }
}

// ---------------- launch ----------------
extern "C" void kernel_launch(void* const* d_in, const int* in_sizes, int n_in,
                              void* d_out, int out_size, void* d_ws, size_t ws_size,
                              hipStream_t stream) {
    const float* x      = (const float*)d_in[0];
    const float* xc     = (const float*)d_in[1];
    const float* W_fc   = (const float*)d_in[2];
    const float* b_fc   = (const float*)d_in[3];
    const float* W_r    = (const float*)d_in[4];
    const float* b_r    = (const float*)d_in[5];
    const float* W_g    = (const float*)d_in[6];
    const float* b_g    = (const float*)d_in[7];
    const float* W_kin  = (const float*)d_in[8];
    const float* b_kin  = (const float*)d_in[9];
    const float* W_kout = (const float*)d_in[10];
    const float* b_kout = (const float*)d_in[11];
    float* yOut = (float*)d_out;

    char* ws = (char*)d_ws;
    float*  stateK = (float*)(ws + 0);                       // 2 MB
    float*  params = (float*)(ws + (2 << 20));               // 2 MB
    ushort* Wt_g   = (ushort*)(ws + (4 << 20));              // 25,344 B (reserve 128 KiB)
    float*  PsA    = (float*)(ws + (4 << 20) + (128 << 10)); // 8,192,000 B each
    float*  PlA    = PsA + (size_t)NT * NS;
    float*  EvA    = PlA + (size_t)NT * NS;
    unsigned int* kmki = (unsigned int*)(EvA + (size_t)NT * NS); // 131,072,000 B
    ushort* keA    = (ushort*)(kmki + (size_t)NT * NS * NH);     // 65,536,000 B

    hipLaunchKernelGGL(kA, dim3(2048), dim3(256), 0, stream,
                       xc, W_fc, b_fc, W_r, b_r, W_g, b_g, b_kin, W_kout,
                       stateK, params, Wt_g);
    hipLaunchKernelGGL(kB, dim3(6400), dim3(256), 0, stream,
                       x, stateK, W_kin, b_kout, Wt_g, kmki, keA, PsA, PlA, EvA);
    hipLaunchKernelGGL(kC, dim3(512), dim3(64), 0, stream,
                       kmki, keA, PsA, PlA, EvA, params, yOut);
}

// Round 4
// 748.145 us; speedup vs baseline: 2.8250x; 1.3152x over previous
//
#include <hip/hip_runtime.h>
#include <hip/hip_bf16.h>

// Problem constants
#define NT   1000
#define NS   2048
#define NH   16
#define NR   8
#define HS   256
#define TOUT 993   // NT - NR + 1

typedef __attribute__((ext_vector_type(8))) short short8;
typedef __attribute__((ext_vector_type(4))) float f32x4;

__device__ __forceinline__ ushort f2bf(float f) {
    union { float f; unsigned int u; } v; v.f = f;
    unsigned int u = v.u;
    return (ushort)((u + 0x7fffu + ((u >> 16) & 1u)) >> 16);
}
__device__ __forceinline__ float bf2f(ushort u) {
    union { unsigned int i; float f; } v; v.i = ((unsigned int)u) << 16; return v.f;
}
// pack two floats -> two bf16 (RNE); lowers to v_cvt_pk_bf16_f32 on gfx950
__device__ __forceinline__ unsigned int packbf2(float lo, float hi) {
    union { __hip_bfloat162 b; unsigned int u; } v;
    v.b = __float22bfloat162_rn(make_float2(lo, hi));
    return v.u;
}
__device__ __forceinline__ float sigf(float x) { return 1.f / (1.f + __expf(-x)); }
__device__ __forceinline__ float fast_tanh(float z) {
    float e = __expf(2.f * z);
    return 1.f - 2.f * __builtin_amdgcn_rcpf(e + 1.f);
}

// ---------------- Kernel A: per-site setup (fp32 inputs) ----------------
__global__ __launch_bounds__(256) void kA(
    const float* __restrict__ xc, const float* __restrict__ W_fc, const float* __restrict__ b_fc,
    const float* __restrict__ W_r, const float* __restrict__ b_r,
    const float* __restrict__ W_g, const float* __restrict__ b_g,
    const float* __restrict__ b_kin, const float* __restrict__ W_kout,
    float* __restrict__ stateK, float* __restrict__ params, ushort* __restrict__ Wt_g)
{
    __shared__ float xcs[32];
    __shared__ float hG[256];
    __shared__ float pGR[288];
    const int s = blockIdx.x, tid = threadIdx.x;

    if (tid < 32) xcs[tid] = xc[s * 32 + tid];
    __syncthreads();

    float acc = b_fc[tid];
#pragma unroll 8
    for (int k = 0; k < 32; ++k) acc = fmaf(xcs[k], W_fc[k * 256 + tid], acc);
    stateK[s * 256 + tid] = acc + b_kin[tid];
    hG[tid] = tanhf(acc);
    __syncthreads();

    for (int j = tid; j < 288; j += 256) {
        const float* W = (j < 144) ? W_g : W_r;
        const float* b = (j < 144) ? b_g : b_r;
        int col = (j < 144) ? j : (j - 144);
        float a = b[col];
#pragma unroll 4
        for (int k = 0; k < 256; ++k) a = fmaf(hG[k], W[k * 144 + col], a);
        pGR[j] = a;
    }
    __syncthreads();

    if (tid < 16) {
        const int h = tid;
        float g0 = pGR[h],       g1 = pGR[16 + h],  g2 = pGR[32 + h];
        float g3 = pGR[48 + h],  g4 = pGR[64 + h],  g5 = pGR[80 + h];
        float g6 = pGR[96 + h],  g7 = pGR[112 + h], g8 = pGR[128 + h];
        float kp = sigf(g0), ksg = sigf(g1), kd = sigf(g2), gd = sigf(g3);
        float t4 = sigf(g4) * 10.f; float gl = t4 * t4 * t4;
        float qb = fmaxf(g5, 0.f) * 0.1f;
        float gi = fminf(fmaxf(g7 * (1.f / 6.f) + 0.5f, 0.f), 1.f) * 0.5f;
        float ge = fmaxf(g8, 0.f);
        float m = g6;
        for (int o = 1; o < 16; o <<= 1) m = fmaxf(m, __shfl_xor(m, o));
        float e = __expf(g6 - m), esum = e;
        for (int o = 1; o < 16; o <<= 1) esum += __shfl_xor(esum, o);
        float ga = e / esum;
        float r[9], rm = -1e30f;
#pragma unroll
        for (int i = 0; i < 9; ++i) { r[i] = pGR[144 + h * 9 + i]; rm = fmaxf(rm, r[i]); }
        float er[9], es = 0.f;
#pragma unroll
        for (int i = 0; i < 9; ++i) { er[i] = __expf(r[i] - rm); es += er[i]; }
        float inv_es = 1.f / es, c = 0.f, wsum = 0.f, w[8];
#pragma unroll
        for (int i = 0; i < 8; ++i) {
            float si = er[i] * inv_es; c += si;
            float wi = fminf(c, 1.f - c + si);
            w[i] = wi; wsum += wi;
        }
        const int base = s * 16 + h;
        params[0 * 32768 + base] = kp;  params[1 * 32768 + base] = ksg;
        params[2 * 32768 + base] = kd;  params[3 * 32768 + base] = gd;
        params[4 * 32768 + base] = gl;  params[5 * 32768 + base] = qb;
        params[6 * 32768 + base] = gi;  params[7 * 32768 + base] = ge;
        float sc = ga / wsum;
#pragma unroll
        for (int i = 0; i < 8; ++i) params[(8 + i) * 32768 + base] = w[i] * sc;
    }

    if (s == 0) {
        for (int i = tid; i < 48 * 256; i += 256) {
            int k = i / 48, col = i - k * 48;
            Wt_g[col * 264 + k] = f2bf(W_kout[i]);   // transpose to bf16, stride 264
        }
    }
}

// ---------------- Kernel B v3: kk-outer, 4-t batch, hoisted weight loads ----------------
// Block = 4 waves x 16 sites x 16 t (4 t per wave). LDS = W_kout^T only.
// Per kk chunk: load stateK slice (8f), W_kin slices (32f), B-frags (3x short8) ONCE,
// reuse across 4 t's. A-fragments computed in registers, zero LDS round-trip.
__global__ __launch_bounds__(256, 3) void kB(
    const float* __restrict__ x,
    const float* __restrict__ stateK, const float* __restrict__ W_kin, const float* __restrict__ b_kout,
    const ushort* __restrict__ Wt_g,
    unsigned int* __restrict__ kmki, ushort* __restrict__ keA,
    float* __restrict__ PsA, float* __restrict__ PlA, float* __restrict__ EvA)
{
    __shared__ ushort Wt[48 * 264];   // 25,344 B
    const int tid = threadIdx.x;
    const int st = blockIdx.x & 127;      // site tile (0..127)
    const int tg = blockIdx.x >> 7;       // t group (0..62)
    const int s0 = st << 4;

    for (int i = tid; i < 3168; i += 256)
        ((uint2*)Wt)[i] = ((const uint2*)Wt_g)[i];
    __syncthreads();

    const int wv = tid >> 6, lane = tid & 63;
    const int mi = lane & 15, quad = lane >> 4;
    const int site = s0 + mi;
    const int t0 = tg * 16 + wv * 4;

    // x features (+ Ps/Pl/Ev from quad 0) for the 4 t's
    float xf[4][4];
#pragma unroll
    for (int ti = 0; ti < 4; ++ti) {
        const int t = t0 + ti;
        const bool tv = (t < 1000);
        const int tc = tv ? t : 999;
        size_t xb = ((size_t)(tc * 2048 + site)) * 6;
        float2 u23 = *(const float2*)(x + xb + 2);
        float2 u45 = *(const float2*)(x + xb + 4);
        xf[ti][0] = u23.x; xf[ti][1] = u23.y; xf[ti][2] = u45.x; xf[ti][3] = u45.y;
        if (lane < 16 && tv) {
            float2 u01 = *(const float2*)(x + xb);
            float fl = u23.y / (u23.y - u23.x + 1e-5f);
            fl = fminf(fmaxf(fl, 0.f), 1.f);
            int ts = tc * 2048 + site;
            PsA[ts] = u01.x * (1.f - fl);
            PlA[ts] = u01.x * fl;
            EvA[ts] = u01.y;
        }
    }

    const float* stp = stateK + site * 256 + quad * 8;
    const float* wkp = W_kin + quad * 8;
    const ushort* Wt0 = Wt + mi * 264 + quad * 8;

    f32x4 acc[4][3];
#pragma unroll
    for (int ti = 0; ti < 4; ++ti)
#pragma unroll
        for (int j = 0; j < 3; ++j) acc[ti][j] = (f32x4){0.f, 0.f, 0.f, 0.f};

    for (int kk = 0; kk < 8; ++kk) {
        const int ko = kk * 32;
        float4 sa  = *(const float4*)(stp + ko);
        float4 sb  = *(const float4*)(stp + ko + 4);
        float4 w0a = *(const float4*)(wkp + ko);
        float4 w0b = *(const float4*)(wkp + ko + 4);
        float4 w1a = *(const float4*)(wkp + 256 + ko);
        float4 w1b = *(const float4*)(wkp + 256 + ko + 4);
        float4 w2a = *(const float4*)(wkp + 512 + ko);
        float4 w2b = *(const float4*)(wkp + 512 + ko + 4);
        float4 w3a = *(const float4*)(wkp + 768 + ko);
        float4 w3b = *(const float4*)(wkp + 768 + ko + 4);
        short8 b0 = *(const short8*)(Wt0 + ko);
        short8 b1 = *(const short8*)(Wt0 + 16 * 264 + ko);
        short8 b2 = *(const short8*)(Wt0 + 32 * 264 + ko);
#pragma unroll
        for (int ti = 0; ti < 4; ++ti) {
            const float x0 = xf[ti][0], x1 = xf[ti][1], x2 = xf[ti][2], x3 = xf[ti][3];
            float z0 = sa.x + x0*w0a.x + x1*w1a.x + x2*w2a.x + x3*w3a.x;
            float z1 = sa.y + x0*w0a.y + x1*w1a.y + x2*w2a.y + x3*w3a.y;
            float z2 = sa.z + x0*w0a.z + x1*w1a.z + x2*w2a.z + x3*w3a.z;
            float z3 = sa.w + x0*w0a.w + x1*w1a.w + x2*w2a.w + x3*w3a.w;
            float z4 = sb.x + x0*w0b.x + x1*w1b.x + x2*w2b.x + x3*w3b.x;
            float z5 = sb.y + x0*w0b.y + x1*w1b.y + x2*w2b.y + x3*w3b.y;
            float z6 = sb.z + x0*w0b.z + x1*w1b.z + x2*w2b.z + x3*w3b.z;
            float z7 = sb.w + x0*w0b.w + x1*w1b.w + x2*w2b.w + x3*w3b.w;
            union { short8 s; unsigned int u[4]; } a;
            a.u[0] = packbf2(fast_tanh(z0), fast_tanh(z1));
            a.u[1] = packbf2(fast_tanh(z2), fast_tanh(z3));
            a.u[2] = packbf2(fast_tanh(z4), fast_tanh(z5));
            a.u[3] = packbf2(fast_tanh(z6), fast_tanh(z7));
            acc[ti][0] = __builtin_amdgcn_mfma_f32_16x16x32_bf16(a.s, b0, acc[ti][0], 0, 0, 0);
            acc[ti][1] = __builtin_amdgcn_mfma_f32_16x16x32_bf16(a.s, b1, acc[ti][1], 0, 0, 0);
            acc[ti][2] = __builtin_amdgcn_mfma_f32_16x16x32_bf16(a.s, b2, acc[ti][2], 0, 0, 0);
        }
    }

    // epilogue: D row = quad*4+reg (site_local), col = mi (head)
    const float bo0 = b_kout[mi], bo1 = b_kout[16 + mi], bo2 = b_kout[32 + mi];
#pragma unroll
    for (int ti = 0; ti < 4; ++ti) {
        const int t = t0 + ti;
        if (t >= 1000) continue;
#pragma unroll
        for (int reg = 0; reg < 4; ++reg) {
            float km = __expf(acc[ti][0][reg] + bo0);
            float ki = fmaxf(acc[ti][1][reg] + bo1, 0.f);
            float ke = __expf(acc[ti][2][reg] + bo2);
            const size_t idx = (size_t)t * 32768 + (s0 + quad * 4 + reg) * 16 + mi;
            kmki[idx] = (unsigned int)f2bf(km) | ((unsigned int)f2bf(ki) << 16);
            keA[idx]  = f2bf(ke);
        }
    }
}

// ---------------- Kernel C v3: scan + FIR; (64,1) bounds so prefetch stays in regs ----------------
__global__ __launch_bounds__(64, 1) void kC(
    const unsigned int* __restrict__ kmki, const ushort* __restrict__ keA,
    const float* __restrict__ PsA, const float* __restrict__ PlA, const float* __restrict__ EvA,
    const float* __restrict__ params, float* __restrict__ yOut)
{
    const int gid = blockIdx.x * 64 + threadIdx.x;
    const int h = gid & 15, s = gid >> 4;

    const float kp  = params[0 * 32768 + gid];
    const float ksg = params[1 * 32768 + gid];
    const float kd  = params[2 * 32768 + gid];
    const float gd  = params[3 * 32768 + gid];
    const float gl  = params[4 * 32768 + gid];
    const float qbv = params[5 * 32768 + gid];
    const float gi  = params[6 * 32768 + gid];
    const float ge  = params[7 * 32768 + gid];
    float wrga[8];
#pragma unroll
    for (int i = 0; i < 8; ++i) wrga[i] = params[(8 + i) * 32768 + gid];

    float Sf = 0.f, Ss = 0.f, Sg = 0.f;
    float qh[8];

    unsigned int ca[8]; ushort ce[8]; float cps[8], cpl[8], cev[8];
#pragma unroll
    for (int i = 0; i < 8; ++i) {
        ca[i] = kmki[(size_t)i * 32768 + gid];
        ce[i] = keA[(size_t)i * 32768 + gid];
        int ts = i * 2048 + s;
        cps[i] = PsA[ts]; cpl[i] = PlA[ts]; cev[i] = EvA[ts];
    }

    for (int tb = 0; tb < 125; ++tb) {
        unsigned int na[8]; ushort ne[8]; float nps[8], npl[8], nev[8];
        const int nb = (tb < 124) ? (tb + 1) * 8 : 0;
#pragma unroll
        for (int i = 0; i < 8; ++i) {
            na[i] = kmki[(size_t)(nb + i) * 32768 + gid];
            ne[i] = keA[(size_t)(nb + i) * 32768 + gid];
            int ts = (nb + i) * 2048 + s;
            nps[i] = PsA[ts]; npl[i] = PlA[ts]; nev[i] = EvA[ts];
        }
#pragma unroll
        for (int i = 0; i < 8; ++i) {
            const int t = tb * 8 + i;
            float km = bf2f((ushort)(ca[i] & 0xffffu));
            float ki = bf2f((ushort)(ca[i] >> 16));
            float ke = bf2f(ce[i]);
            float ps = cps[i], pl = cpl[i], ev = cev[i];

            Sf += ps;
            float qf = fminf(Sf, km); Sf -= qf;
            float inflow = qf + pl;
            float qd = inflow * gi;
            Ss += inflow * (1.f - gi);
            float E = fminf(fmaxf(Ss, 0.f), ev * ke * ge); Ss -= E;
            float qi = fminf(ki, fmaxf(Ss, 0.f)); Ss -= qi;
            float qp = kp * fmaxf(Ss - gl, 0.f);
            float qsa = ksg * fminf(fmaxf(Ss, 0.f), gl);
            Ss -= qp + qsa;
            Sg += qsa * gd;
            float qg = kd * Sg + qbv;
            Sg *= (1.f - kd);
            float q = qp + qsa * (1.f - gd) + qg + qd + qi;
            qh[i] = q;

            if (t >= 7) {
                float v = 0.f;
#pragma unroll
                for (int k = 0; k < 8; ++k) v = fmaf(wrga[k], qh[(i - k) & 7], v);
                v += __shfl_xor(v, 1); v += __shfl_xor(v, 2);
                v += __shfl_xor(v, 4); v += __shfl_xor(v, 8);
                if (h == 0) yOut[(size_t)(t - 7) * 2048 + s] = v;
            }
        }
#pragma unroll
        for (int i = 0; i < 8; ++i) {
            ca[i] = na[i]; ce[i] = ne[i];
            cps[i] = nps[i]; cpl[i] = npl[i]; cev[i] = nev[i];
        }
    }
}

// ---------------- launch ----------------
extern "C" void kernel_launch(void* const* d_in, const int* in_sizes, int n_in,
                              void* d_out, int out_size, void* d_ws, size_t ws_size,
                              hipStream_t stream) {
    const float* x      = (const float*)d_in[0];
    const float* xc     = (const float*)d_in[1];
    const float* W_fc   = (const float*)d_in[2];
    const float* b_fc   = (const float*)d_in[3];
    const float* W_r    = (const float*)d_in[4];
    const float* b_r    = (const float*)d_in[5];
    const float* W_g    = (const float*)d_in[6];
    const float* b_g    = (const float*)d_in[7];
    const float* W_kin  = (const float*)d_in[8];
    const float* b_kin  = (const float*)d_in[9];
    const float* W_kout = (const float*)d_in[10];
    const float* b_kout = (const float*)d_in[11];
    float* yOut = (float*)d_out;

    char* ws = (char*)d_ws;
    float*  stateK = (float*)(ws + 0);                       // 2 MB
    float*  params = (float*)(ws + (2 << 20));               // 2 MB
    ushort* Wt_g   = (ushort*)(ws + (4 << 20));              // 25,344 B (reserve 128 KiB)
    float*  PsA    = (float*)(ws + (4 << 20) + (128 << 10)); // 8,192,000 B each
    float*  PlA    = PsA + (size_t)NT * NS;
    float*  EvA    = PlA + (size_t)NT * NS;
    unsigned int* kmki = (unsigned int*)(EvA + (size_t)NT * NS); // 131,072,000 B
    ushort* keA    = (ushort*)(kmki + (size_t)NT * NS * NH);     // 65,536,000 B

    hipLaunchKernelGGL(kA, dim3(2048), dim3(256), 0, stream,
                       xc, W_fc, b_fc, W_r, b_r, W_g, b_g, b_kin, W_kout,
                       stateK, params, Wt_g);
    hipLaunchKernelGGL(kB, dim3(128 * 63), dim3(256), 0, stream,
                       x, stateK, W_kin, b_kout, Wt_g, kmki, keA, PsA, PlA, EvA);
    hipLaunchKernelGGL(kC, dim3(512), dim3(64), 0, stream,
                       kmki, keA, PsA, PlA, EvA, params, yOut);
}